// Round 17
// baseline (256.870 us; speedup 1.0000x reference)
//
#include <hip/hip_runtime.h>
#include <math.h>

#define SEQ   2048
#define DM    1024
#define LDQKV 3072
#define MTOK  4096   // B*T

typedef float  f32x4   __attribute__((ext_vector_type(4)));
typedef __bf16 bf16x8  __attribute__((ext_vector_type(8)));
typedef short  short8  __attribute__((ext_vector_type(8)));
typedef short  short4v __attribute__((ext_vector_type(4)));

__device__ __forceinline__ short f2bf(float f) {
  union { float f; unsigned u; } v; v.f = f;
  unsigned r = v.u + 0x7fffu + ((v.u >> 16) & 1u);
  return (short)(r >> 16);
}

__device__ __forceinline__ void gl_lds16(const void* g, void* l) {
  __builtin_amdgcn_global_load_lds(
      (const __attribute__((address_space(1))) void*)g,
      (__attribute__((address_space(3))) void*)l, 16, 0, 0);
}

__device__ __forceinline__ f32x4 mfma_bf16(bf16x8 a, bf16x8 b, f32x4 c) {
  return __builtin_amdgcn_mfma_f32_16x16x32_bf16(a, b, c, 0, 0, 0);
}

// GELU exact-erf via Abramowitz-Stegun 7.1.26 (|eps| <= 1.5e-7)
__device__ __forceinline__ float gelu_f(float x) {
  const float z  = x * 0.70710678118654752f;
  const float az = fabsf(z);
  const float t  = __builtin_amdgcn_rcpf(fmaf(0.3275911f, az, 1.0f));
  float p = fmaf(1.061405429f, t, -1.453152027f);
  p = fmaf(p, t, 1.421413741f);
  p = fmaf(p, t, -0.284496736f);
  p = fmaf(p, t, 0.254829592f);
  p = p * t;
  const float e = __builtin_amdgcn_exp2f(az * az * -1.4426950408889634f);
  float erfp = fmaf(-p, e, 1.0f);
  erfp = (z < 0.f) ? -erfp : erfp;
  return x * fmaf(0.5f, erfp, 0.5f);
}

// ---------------------------------------------------------------------------
// Fused weight cast+transpose, ALL 6 weights in one launch (3072 blocks).
// ---------------------------------------------------------------------------
__global__ __launch_bounds__(256) void transpose_all_k(
    const float* __restrict__ Wq, const float* __restrict__ Wk,
    const float* __restrict__ Wv, const float* __restrict__ Wo,
    const float* __restrict__ W1, const float* __restrict__ W2,
    short* __restrict__ Wqt, short* __restrict__ Wkt, short* __restrict__ Wvt,
    short* __restrict__ Wot, short* __restrict__ W1t, short* __restrict__ W2t)
{
  const int bid = blockIdx.x;
  const float* W; short* Wt; int K, N, nx, ky;
  if (bid < 1024) {
    const int m = bid >> 8, r = bid & 255;
    W  = (m == 0) ? Wq : (m == 1) ? Wk : (m == 2) ? Wv : Wo;
    Wt = (m == 0) ? Wqt : (m == 1) ? Wkt : (m == 2) ? Wvt : Wot;
    K = 1024; N = 1024; nx = r & 15; ky = r >> 4;
  } else if (bid < 2048) {
    const int r = bid - 1024;
    W = W1; Wt = W1t; K = 1024; N = 4096; nx = r & 63; ky = r >> 6;
  } else {
    const int r = bid - 2048;
    W = W2; Wt = W2t; K = 4096; N = 1024; nx = r & 15; ky = r >> 4;
  }
  const int n0 = nx * 64, k0 = ky * 64;

  __shared__ float tile[64][65];
  const int tid = threadIdx.x;
  const int lr = tid >> 4, lc = (tid & 15) * 4;
#pragma unroll
  for (int i = 0; i < 4; i++) {
    const float4 v = *(const float4*)&W[(size_t)(k0 + lr + i * 16) * N + n0 + lc];
    tile[lr + i * 16][lc]     = v.x;
    tile[lr + i * 16][lc + 1] = v.y;
    tile[lr + i * 16][lc + 2] = v.z;
    tile[lr + i * 16][lc + 3] = v.w;
  }
  __syncthreads();
  const int nr = tid >> 3, ks = (tid & 7) * 8;
#pragma unroll
  for (int i = 0; i < 2; i++) {
    short8 o;
#pragma unroll
    for (int j = 0; j < 8; j++) o[j] = f2bf(tile[ks + j][nr + i * 32]);
    *(short8*)&Wt[(size_t)(n0 + nr + i * 32) * K + k0 + ks] = o;
  }
}

// ---------------------------------------------------------------------------
// LayerNorm row kernel: x fp32 [rows,1024] -> out bf16
// ---------------------------------------------------------------------------
__global__ __launch_bounds__(256) void ln_k(
    const float* __restrict__ x, const float* __restrict__ g,
    const float* __restrict__ b, short* __restrict__ out)
{
  const int row = blockIdx.x;
  const int tid = threadIdx.x;
  const float4 v = ((const float4*)(x + (size_t)row * DM))[tid];
  float s  = v.x + v.y + v.z + v.w;
  float ss = v.x * v.x + v.y * v.y + v.z * v.z + v.w * v.w;
#pragma unroll
  for (int m = 32; m >= 1; m >>= 1) { s += __shfl_xor(s, m); ss += __shfl_xor(ss, m); }
  __shared__ float red[8];
  const int wid = tid >> 6;
  if ((tid & 63) == 0) { red[wid] = s; red[4 + wid] = ss; }
  __syncthreads();
  s  = red[0] + red[1] + red[2] + red[3];
  ss = red[4] + red[5] + red[6] + red[7];
  const float mu  = s * (1.f / DM);
  const float var = ss * (1.f / DM) - mu * mu;
  const float rs  = rsqrtf(var + 1e-5f);
  const float4 gv = ((const float4*)g)[tid];
  const float4 bv = ((const float4*)b)[tid];
  short4v o;
  o[0] = f2bf((v.x - mu) * rs * gv.x + bv.x);
  o[1] = f2bf((v.y - mu) * rs * gv.y + bv.y);
  o[2] = f2bf((v.z - mu) * rs * gv.z + bv.z);
  o[3] = f2bf((v.w - mu) * rs * gv.w + bv.w);
  *(short4v*)(out + (size_t)row * DM + tid * 4) = o;
}

__global__ __launch_bounds__(256) void concat_bias_k(
    const float* __restrict__ bq, const float* __restrict__ bk,
    const float* __restrict__ bv, float* __restrict__ o)
{
  int i = blockIdx.x * 256 + threadIdx.x;
  if (i < 3072) {
    float v = (i < 1024) ? bq[i] : (i < 2048 ? bk[i - 1024] : bv[i - 2048]);
    o[i] = v;
  }
}

// ---------------------------------------------------------------------------
// V transpose: V region of QKV [token][h*64+d] -> Vt [(b*16+h)*64+d][2048]
// ---------------------------------------------------------------------------
__global__ __launch_bounds__(256) void vtrans_k(
    const short* __restrict__ V, short* __restrict__ Vt)
{
  const int b = blockIdx.z, h = blockIdx.y, t0 = blockIdx.x * 64;
  __shared__ short tile[64][72];
  const int tid = threadIdx.x;
  const int r = tid >> 2, c = (tid & 3) * 16;
  const short* src = V + (size_t)(b * SEQ + t0 + r) * LDQKV + h * 64 + c;
  *(short8*)&tile[r][c]     = *(const short8*)src;
  *(short8*)&tile[r][c + 8] = *(const short8*)(src + 8);
  __syncthreads();
  const int d = tid >> 2;
  short8 o0, o1;
#pragma unroll
  for (int k = 0; k < 8; k++) o0[k] = tile[c + k][d];
#pragma unroll
  for (int k = 0; k < 8; k++) o1[k] = tile[c + 8 + k][d];
  short* dst = Vt + (((size_t)(b * 16 + h) * 64) + d) * 2048 + t0 + c;
  *(short8*)dst       = o0;
  *(short8*)(dst + 8) = o1;
}

// ---------------------------------------------------------------------------
// GEMM 256x256, BK=64, 8 waves, 2-phase double-buffered (proven; qkv).
// ---------------------------------------------------------------------------
template <bool GELU_, bool RESID, bool OUTBF16>
__global__ __launch_bounds__(512) void gemm256(
    const short* __restrict__ A, const short* __restrict__ Bt,
    const float* __restrict__ bias, const float* __restrict__ resid,
    void* __restrict__ Cout, int M, int N, int K)
{
  __shared__ __align__(16) short Atile[2][256 * 64];
  __shared__ __align__(16) short Btile[2][256 * 64];

  const int tid = threadIdx.x, lane = tid & 63, wid = tid >> 6;
  const int wm = wid >> 2, wn = wid & 3;

  const int nbn = N >> 8;
  const int chunk = gridDim.x >> 3;
  const int swz = (blockIdx.x & 7) * chunk + (blockIdx.x >> 3);
  const int bm = (swz / nbn) * 256;
  const int bn = (swz % nbn) * 256;

  f32x4 acc[8][4] = {};

  const int srow  = wid * 8 + (lane >> 3);
  const int sslot = (lane & 7) ^ ((lane >> 3) & 7);
  const short* Asrc = A  + (size_t)(bm + srow) * K + sslot * 8;
  const short* Bsrc = Bt + (size_t)(bn + srow) * K + sslot * 8;

#define STAGE256(buf, k0)                                                     \
  {                                                                           \
    _Pragma("unroll")                                                         \
    for (int j = 0; j < 4; j++) {                                             \
      gl_lds16(Asrc + (size_t)(j * 64) * K + (k0), &Atile[buf][(j * 64 + wid * 8) * 64]); \
      gl_lds16(Bsrc + (size_t)(j * 64) * K + (k0), &Btile[buf][(j * 64 + wid * 8) * 64]); \
    }                                                                         \
  }

  const int aRowBase = (wm * 128 + (lane & 15)) * 128;
  const int bRowBase = (wn * 64  + (lane & 15)) * 128;
  const int slot0 = (((lane >> 4)    ) ^ (lane & 7)) * 16;
  const int slot1 = (((lane >> 4) + 4) ^ (lane & 7)) * 16;

#define COMPUTE256(buf)                                                       \
  {                                                                           \
    const char* Ab_ = (const char*)&Atile[buf][0];                            \
    const char* Bb_ = (const char*)&Btile[buf][0];                            \
    _Pragma("unroll")                                                         \
    for (int ks = 0; ks < 2; ks++) {                                          \
      const int sl = ks ? slot1 : slot0;                                      \
      bf16x8 a[8], b[4];                                                      \
      _Pragma("unroll")                                                       \
      for (int mi = 0; mi < 8; mi++)                                          \
        a[mi] = *(const bf16x8*)(Ab_ + aRowBase + mi * 2048 + sl);            \
      _Pragma("unroll")                                                       \
      for (int ni = 0; ni < 4; ni++)                                          \
        b[ni] = *(const bf16x8*)(Bb_ + bRowBase + ni * 2048 + sl);            \
      __builtin_amdgcn_s_setprio(1);                                          \
      _Pragma("unroll")                                                       \
      for (int mi = 0; mi < 8; mi++)                                          \
        _Pragma("unroll")                                                     \
        for (int ni = 0; ni < 4; ni++)                                        \
          acc[mi][ni] = mfma_bf16(a[mi], b[ni], acc[mi][ni]);                 \
      __builtin_amdgcn_s_setprio(0);                                          \
    }                                                                         \
  }

  STAGE256(0, 0);
  __syncthreads();

  int cur = 0;
  const int ntiles = K >> 6;
  for (int t = 1; t < ntiles; ++t) {
    STAGE256(cur ^ 1, t * 64);
    COMPUTE256(cur);
    __syncthreads();
    cur ^= 1;
  }
  COMPUTE256(cur);

#pragma unroll
  for (int mi = 0; mi < 8; mi++) {
#pragma unroll
    for (int ni = 0; ni < 4; ni++) {
      const int col = bn + wn * 64 + ni * 16 + (lane & 15);
      const float bs = bias[col];
#pragma unroll
      for (int j = 0; j < 4; j++) {
        const int row = bm + wm * 128 + mi * 16 + (lane >> 4) * 4 + j;
        float v = acc[mi][ni][j] + bs;
        if (GELU_) v = gelu_f(v);
        if (RESID) v += resid[(size_t)row * N + col];
        if (OUTBF16) ((short*)Cout)[(size_t)row * N + col] = f2bf(v);
        else         ((float*)Cout)[(size_t)row * N + col] = v;
      }
    }
  }
#undef STAGE256
#undef COMPUTE256
}

// ---------------------------------------------------------------------------
// GEMM 256x256, BK=32, 8 waves, 4-BUFFER ring, DEPTH-3 prefetch, counted
// vmcnt + raw s_barrier + sched_barrier(0). (Proven on ffn1.)
// ---------------------------------------------------------------------------
template <bool GELU_, bool RESID, bool OUTBF16>
__global__ __launch_bounds__(512) void gemm256d3(
    const short* __restrict__ A, const short* __restrict__ Bt,
    const float* __restrict__ bias, const float* __restrict__ resid,
    void* __restrict__ Cout, int M, int N, int K)
{
  __shared__ __align__(16) short Ash[4][256 * 32];   // 4 x 16 KB
  __shared__ __align__(16) short Bsh[4][256 * 32];   // 4 x 16 KB

  const int tid = threadIdx.x, lane = tid & 63, wid = tid >> 6;
  const int wm = wid >> 2, wn = wid & 3;

  const int nbn = N >> 8;
  const int chunk = gridDim.x >> 3;
  const int swz = (blockIdx.x & 7) * chunk + (blockIdx.x >> 3);
  const int bm = (swz / nbn) * 256;
  const int bn = (swz % nbn) * 256;

  f32x4 acc[8][4] = {};

  const int srow = tid >> 2;
  const int scol = ((tid & 3) ^ ((srow >> 1) & 3)) * 8;
  const short* Asrc = A  + (size_t)(bm + srow) * K + scol;
  const short* Bsrc = Bt + (size_t)(bn + srow) * K + scol;
  const int d0 = (wid * 16) * 32, d1 = (128 + wid * 16) * 32;

#define STAGE_D3(buf, k0)                                                     \
  {                                                                           \
    gl_lds16(Asrc + (k0),                   &Ash[buf][d0]);                   \
    gl_lds16(Asrc + (size_t)128 * K + (k0), &Ash[buf][d1]);                   \
    gl_lds16(Bsrc + (k0),                   &Bsh[buf][d0]);                   \
    gl_lds16(Bsrc + (size_t)128 * K + (k0), &Bsh[buf][d1]);                   \
  }

  const int rslot = ((lane >> 4) ^ ((lane >> 1) & 3)) * 8;
  const int aOff  = (wm * 128 + (lane & 15)) * 32 + rslot;
  const int bOff  = (wn * 64  + (lane & 15)) * 32 + rslot;

#define COMPUTE_D3(buf)                                                       \
  {                                                                           \
    const short* Ab_ = &Ash[buf][0];                                          \
    const short* Bb_ = &Bsh[buf][0];                                          \
    bf16x8 a[8], b[4];                                                        \
    _Pragma("unroll")                                                         \
    for (int mi = 0; mi < 8; mi++)                                            \
      a[mi] = *(const bf16x8*)(Ab_ + aOff + mi * 512);                        \
    _Pragma("unroll")                                                         \
    for (int ni = 0; ni < 4; ni++)                                            \
      b[ni] = *(const bf16x8*)(Bb_ + bOff + ni * 512);                        \
    __builtin_amdgcn_s_setprio(1);                                            \
    _Pragma("unroll")                                                         \
    for (int mi = 0; mi < 8; mi++)                                            \
      _Pragma("unroll")                                                       \
      for (int ni = 0; ni < 4; ni++)                                          \
        acc[mi][ni] = mfma_bf16(a[mi], b[ni], acc[mi][ni]);                   \
    __builtin_amdgcn_s_setprio(0);                                            \
  }

  const int nt = K >> 5;

  STAGE_D3(0, 0);
  STAGE_D3(1, 32);
  STAGE_D3(2, 64);
  asm volatile("s_waitcnt vmcnt(8)" ::: "memory");
  __builtin_amdgcn_s_barrier();
  __builtin_amdgcn_sched_barrier(0);

  for (int t = 0; t < nt; ++t) {
    if (t + 3 < nt) STAGE_D3((t + 3) & 3, (t + 3) * 32);
    COMPUTE_D3(t & 3);
    if (t + 3 < nt)      { asm volatile("s_waitcnt vmcnt(8)" ::: "memory"); }
    else if (t + 2 < nt) { asm volatile("s_waitcnt vmcnt(4)" ::: "memory"); }
    else if (t + 1 < nt) { asm volatile("s_waitcnt vmcnt(0)" ::: "memory"); }
    __builtin_amdgcn_s_barrier();
    __builtin_amdgcn_sched_barrier(0);
  }

#pragma unroll
  for (int mi = 0; mi < 8; mi++) {
#pragma unroll
    for (int ni = 0; ni < 4; ni++) {
      const int col = bn + wn * 64 + ni * 16 + (lane & 15);
      const float bs = bias[col];
#pragma unroll
      for (int j = 0; j < 4; j++) {
        const int row = bm + wm * 128 + mi * 16 + (lane >> 4) * 4 + j;
        float v = acc[mi][ni][j] + bs;
        if (GELU_) v = gelu_f(v);
        if (RESID) v += resid[(size_t)row * N + col];
        if (OUTBF16) ((short*)Cout)[(size_t)row * N + col] = f2bf(v);
        else         ((float*)Cout)[(size_t)row * N + col] = v;
      }
    }
  }
#undef STAGE_D3
#undef COMPUTE_D3
}

// ---------------------------------------------------------------------------
// GEMM 128x128, BK=64, 8 waves (2Mx4N, wave tile 64x32, 16 MFMA/step),
// 4-BUFFER ring depth-3 counted vmcnt (d3 schedule) for narrow-N shapes
// (o-proj, ffn2). Grid (M/128)*(N/128) = 256 blocks. LDS 128 KB, 1 block/CU.
// Reuses gemm256's proven 128B-row swizzle (0 conflicts) and staging map.
// ---------------------------------------------------------------------------
template <bool GELU_, bool RESID, bool OUTBF16>
__global__ __launch_bounds__(512) void gemm128d3(
    const short* __restrict__ A, const short* __restrict__ Bt,
    const float* __restrict__ bias, const float* __restrict__ resid,
    void* __restrict__ Cout, int M, int N, int K)
{
  __shared__ __align__(16) short Ash[4][128 * 64];   // 4 x 16 KB
  __shared__ __align__(16) short Bsh[4][128 * 64];   // 4 x 16 KB

  const int tid = threadIdx.x, lane = tid & 63, wid = tid >> 6;
  const int wm = wid >> 2, wn = wid & 3;          // 2 x 4 wave grid

  const int nbn = N >> 7;
  const int chunk = gridDim.x >> 3;
  const int swz = (blockIdx.x & 7) * chunk + (blockIdx.x >> 3);
  const int bm = (swz / nbn) * 128;
  const int bn = (swz % nbn) * 128;

  f32x4 acc[4][2] = {};

  // staging (gemm256 map): each wave-instr covers 8 rows; j in {0,1} x 64 rows
  const int srow  = wid * 8 + (lane >> 3);          // 0..63
  const int sslot = (lane & 7) ^ ((lane >> 3) & 7); // col ^ (row&7)
  const short* Asrc = A  + (size_t)(bm + srow) * K + sslot * 8;
  const short* Bsrc = Bt + (size_t)(bn + srow) * K + sslot * 8;

#define STAGE_128(buf, k0)                                                    \
  {                                                                           \
    gl_lds16(Asrc + (k0),                  &Ash[buf][(wid * 8) * 64]);        \
    gl_lds16(Asrc + (size_t)64 * K + (k0), &Ash[buf][(64 + wid * 8) * 64]);   \
    gl_lds16(Bsrc + (k0),                  &Bsh[buf][(wid * 8) * 64]);        \
    gl_lds16(Bsrc + (size_t)64 * K + (k0), &Bsh[buf][(64 + wid * 8) * 64]);   \
  }

  const int aRowBase = (wm * 64 + (lane & 15)) * 128;   // bytes, 128B rows
  const int bRowBase = (wn * 32 + (lane & 15)) * 128;
  const int slot0 = (((lane >> 4)    ) ^ (lane & 7)) * 16;
  const int slot1 = (((lane >> 4) + 4) ^ (lane & 7)) * 16;

#define COMPUTE_128(buf)                                                      \
  {                                                                           \
    const char* Ab_ = (const char*)&Ash[buf][0];                              \
    const char* Bb_ = (const char*)&Bsh[buf][0];                              \
    _Pragma("unroll")                                                         \
    for (int ks = 0; ks < 2; ks++) {                                          \
      const int sl = ks ? slot1 : slot0;                                      \
      bf16x8 a[4], b[2];                                                      \
      _Pragma("unroll")                                                       \
      for (int mi = 0; mi < 4; mi++)                                          \
        a[mi] = *(const bf16x8*)(Ab_ + aRowBase + mi * 2048 + sl);            \
      _Pragma("unroll")                                                       \
      for (int ni = 0; ni < 2; ni++)                                          \
        b[ni] = *(const bf16x8*)(Bb_ + bRowBase + ni * 2048 + sl);            \
      __builtin_amdgcn_s_setprio(1);                                          \
      _Pragma("unroll")                                                       \
      for (int mi = 0; mi < 4; mi++)                                          \
        _Pragma("unroll")                                                     \
        for (int ni = 0; ni < 2; ni++)                                        \
          acc[mi][ni] = mfma_bf16(a[mi], b[ni], acc[mi][ni]);                 \
      __builtin_amdgcn_s_setprio(0);                                          \
    }                                                                         \
  }

  const int nt = K >> 6;   // 16 (oproj) / 64 (ffn2)

  STAGE_128(0, 0);
  STAGE_128(1, 64);
  STAGE_128(2, 128);
  asm volatile("s_waitcnt vmcnt(8)" ::: "memory");
  __builtin_amdgcn_s_barrier();
  __builtin_amdgcn_sched_barrier(0);

  for (int t = 0; t < nt; ++t) {
    if (t + 3 < nt) STAGE_128((t + 3) & 3, (t + 3) * 64);
    COMPUTE_128(t & 3);
    if (t + 3 < nt)      { asm volatile("s_waitcnt vmcnt(8)" ::: "memory"); }
    else if (t + 2 < nt) { asm volatile("s_waitcnt vmcnt(4)" ::: "memory"); }
    else if (t + 1 < nt) { asm volatile("s_waitcnt vmcnt(0)" ::: "memory"); }
    __builtin_amdgcn_s_barrier();
    __builtin_amdgcn_sched_barrier(0);
  }

#pragma unroll
  for (int mi = 0; mi < 4; mi++) {
#pragma unroll
    for (int ni = 0; ni < 2; ni++) {
      const int col = bn + wn * 32 + ni * 16 + (lane & 15);
      const float bs = bias[col];
#pragma unroll
      for (int j = 0; j < 4; j++) {
        const int row = bm + wm * 64 + mi * 16 + (lane >> 4) * 4 + j;
        float v = acc[mi][ni][j] + bs;
        if (GELU_) v = gelu_f(v);
        if (RESID) v += resid[(size_t)row * N + col];
        if (OUTBF16) ((short*)Cout)[(size_t)row * N + col] = f2bf(v);
        else         ((float*)Cout)[(size_t)row * N + col] = v;
      }
    }
  }
#undef STAGE_128
#undef COMPUTE_128
}

// ---------------------------------------------------------------------------
// Flash attention v4.1 (proven r14 best): 8 waves / 128 q-rows, swapped-QK^T,
// KVBLK=128, defer-max, in-register P, K+V dbuf LDS, chunked XCD swizzle.
// ---------------------------------------------------------------------------
__global__ __launch_bounds__(512, 4) void attn_k(
    const short* __restrict__ Qg, const short* __restrict__ Kg,
    const short* __restrict__ Vt, short* __restrict__ Og)
{
  const int phys = blockIdx.x;
  const int lg = (phys & 7) * 64 + (phys >> 3);
  const int q0 = (lg & 15) * 128;
  const int h  = (lg >> 4) & 15;
  const int b  = lg >> 8;

  const int tid = threadIdx.x, lane = tid & 63, w = tid >> 6;
  const int qlane = lane & 15, g = lane >> 4;

  __shared__ __align__(16) short Kl[2][128 * 64];
  __shared__ __align__(16) short Vl[2][64 * 128];

  const size_t qrow = (size_t)(b * SEQ + q0 + w * 16 + qlane) * LDQKV + h * 64;
  const bf16x8 qf0 = *(const bf16x8*)&Qg[qrow + g * 8];
  const bf16x8 qf1 = *(const bf16x8*)&Qg[qrow + 32 + g * 8];

  const int kslot = (lane & 7) ^ ((lane >> 3) & 7);
  const short* Kg_a[2];
#pragma unroll
  for (int i = 0; i < 2; i++) {
    const int r  = i * 64 + w * 8 + (lane >> 3);
    const int kc = r >> 4, gr = (r >> 2) & 3, jr = r & 3;
    const int a  = 32 * (kc & 3) + 8 * gr + 4 * (kc >> 2) + jr;
    Kg_a[i] = Kg + ((size_t)(b * SEQ) + a) * LDQKV + h * 64 + kslot * 8;
  }
  const short* Vg_s[2];
#pragma unroll
  for (int i = 0; i < 2; i++) {
    const int d  = i * 32 + w * 4 + (lane >> 4);
    const int vs = (lane & 15) ^ (d & 15);
    Vg_s[i] = Vt + ((size_t)(b * 16 + h) * 64 + d) * 2048 + vs * 8;
  }

  float m_run = -1e30f, l_run = 0.f;
  f32x4 oacc[4] = {};
  const float C = 0.125f * 1.44269504088896f;

#pragma unroll
  for (int i = 0; i < 2; i++) {
    gl_lds16(Kg_a[i], &Kl[0][(i * 64 + w * 8) * 64]);
    gl_lds16(Vg_s[i], &Vl[0][(i * 32 + w * 4) * 128]);
  }
  __syncthreads();

  int cur = 0;
  for (int kt = 0; kt < SEQ; kt += 128) {
    const int nxt = cur ^ 1;
    if (kt + 128 < SEQ) {
#pragma unroll
      for (int i = 0; i < 2; i++) {
        gl_lds16(Kg_a[i] + (size_t)(kt + 128) * LDQKV, &Kl[nxt][(i * 64 + w * 8) * 64]);
        gl_lds16(Vg_s[i] + (kt + 128),                 &Vl[nxt][(i * 32 + w * 4) * 128]);
      }
    }
    const char* KbC = (const char*)&Kl[cur][0];
    const char* VbC = (const char*)&Vl[cur][0];

    f32x4 s[8];
#pragma unroll
    for (int kc = 0; kc < 8; kc++) {
      const int kr = kc * 16 + qlane;
      const char* kp = KbC + kr * 128;
      const int sw = (kr & 7) << 4;
      bf16x8 kf0 = *(const bf16x8*)(kp + ((g * 16) ^ sw));
      bf16x8 kf1 = *(const bf16x8*)(kp + ((64 + g * 16) ^ sw));
      f32x4 z = {};
      z = mfma_bf16(kf0, qf0, z);
      z = mfma_bf16(kf1, qf1, z);
      s[kc] = z;
    }

    f32x4 m4 = s[0];
#pragma unroll
    for (int kc = 1; kc < 8; kc++) {
      m4[0] = fmaxf(m4[0], s[kc][0]); m4[1] = fmaxf(m4[1], s[kc][1]);
      m4[2] = fmaxf(m4[2], s[kc][2]); m4[3] = fmaxf(m4[3], s[kc][3]);
    }
    float mt = fmaxf(fmaxf(m4[0], m4[1]), fmaxf(m4[2], m4[3]));
    mt = fmaxf(mt, __shfl_xor(mt, 16));
    mt = fmaxf(mt, __shfl_xor(mt, 32));

    if (!__all(mt - m_run <= 40.0f)) {
      const float mnew = fmaxf(m_run, mt);
      const float r = __builtin_amdgcn_exp2f((m_run - mnew) * C);
      m_run = mnew;
      l_run *= r;
#pragma unroll
      for (int j = 0; j < 4; j++) {
        const float rj = __shfl(r, g * 4 + j);
#pragma unroll
        for (int dt = 0; dt < 4; dt++) oacc[dt][j] *= rj;
      }
    }

    const float nmc = -m_run * C;
    float rs = 0.f;
    unsigned pw[4][4];
#pragma unroll
    for (int kc = 0; kc < 8; kc++) {
      f32x4 p;
#pragma unroll
      for (int j = 0; j < 4; j++) p[j] = __builtin_amdgcn_exp2f(fmaf(s[kc][j], C, nmc));
      rs += (p[0] + p[1]) + (p[2] + p[3]);
      unsigned w0, w1;
      asm("v_cvt_pk_bf16_f32 %0, %1, %2" : "=v"(w0) : "v"(p[0]), "v"(p[1]));
      asm("v_cvt_pk_bf16_f32 %0, %1, %2" : "=v"(w1) : "v"(p[2]), "v"(p[3]));
      pw[kc & 3][2 * (kc >> 2) + 0] = w0;
      pw[kc & 3][2 * (kc >> 2) + 1] = w1;
    }
    rs += __shfl_xor(rs, 16);
    rs += __shfl_xor(rs, 32);
    l_run += rs;

#pragma unroll
    for (int ks = 0; ks < 4; ks++) {
      union { unsigned u[4]; bf16x8 v; } pf;
      pf.u[0] = pw[ks][0]; pf.u[1] = pw[ks][1];
      pf.u[2] = pw[ks][2]; pf.u[3] = pw[ks][3];
#pragma unroll
      for (int dt = 0; dt < 4; dt++) {
        const int vr = dt * 16 + qlane;
        bf16x8 vf = *(const bf16x8*)(VbC + vr * 256 + ((64 * ks + 16 * g) ^ ((vr & 15) << 4)));
        oacc[dt] = mfma_bf16(pf.v, vf, oacc[dt]);
      }
    }

    __syncthreads();
    cur = nxt;
  }

  const float linv = 1.f / l_run;
#pragma unroll
  for (int j = 0; j < 4; j++) {
    const float lj = __shfl(linv, g * 4 + j);
    const int tok = q0 + w * 16 + g * 4 + j;
#pragma unroll
    for (int dt = 0; dt < 4; dt++)
      Og[(size_t)(b * SEQ + tok) * DM + h * 64 + dt * 16 + qlane] = f2bf(oacc[dt][j] * lj);
  }
}

// ---------------------------------------------------------------------------
extern "C" void kernel_launch(void* const* d_in, const int* in_sizes, int n_in,
                              void* d_out, int out_size, void* d_ws, size_t ws_size,
                              hipStream_t stream)
{
  const float* x    = (const float*)d_in[0];
  const float* Wq   = (const float*)d_in[1];
  const float* bq   = (const float*)d_in[2];
  const float* Wk   = (const float*)d_in[3];
  const float* bk   = (const float*)d_in[4];
  const float* Wv   = (const float*)d_in[5];
  const float* bv   = (const float*)d_in[6];
  const float* Wo   = (const float*)d_in[7];
  const float* bo   = (const float*)d_in[8];
  const float* W1   = (const float*)d_in[9];
  const float* b1   = (const float*)d_in[10];
  const float* W2   = (const float*)d_in[11];
  const float* b2   = (const float*)d_in[12];
  const float* ln1g = (const float*)d_in[13];
  const float* ln1b = (const float*)d_in[14];
  const float* ln2g = (const float*)d_in[15];
  const float* ln2b = (const float*)d_in[16];

  char* ws = (char*)d_ws;
  const size_t MB = 1024 * 1024;
  short* Wqkvt = (short*)(ws + 0 * MB);           // [3072][1024] bf16
  short* Wqt   = Wqkvt;
  short* Wkt   = (short*)(ws + 2 * MB);
  short* Wvt   = (short*)(ws + 4 * MB);
  short* Wot   = (short*)(ws + 6 * MB);           // [1024][1024]
  short* W1t   = (short*)(ws + 8 * MB);           // [4096][1024]
  short* W2t   = (short*)(ws + 16 * MB);          // [1024][4096]
  short* hbuf  = (short*)(ws + 24 * MB);          // [4096][1024] bf16
  short* QKV   = (short*)(ws + 32 * MB);          // [4096][3072] bf16
  short* AO    = (short*)(ws + 56 * MB);          // [4096][1024] bf16
  float* x1    = (float*)(ws + 64 * MB);          // [4096][1024] fp32 (after attn)
  short* Vtb   = (short*)(ws + 64 * MB);          // [2048][2048] bf16 Vt
  float* bqkv  = (float*)(ws + 80 * MB);          // [3072] fp32
  short* gbuf  = (short*)(ws + 32 * MB);          // [4096][4096] bf16, aliases QKV+AO

  dim3 tb(256);

  // all 6 weight transposes in one launch
  transpose_all_k<<<dim3(3072), tb, 0, stream>>>(
      Wq, Wk, Wv, Wo, W1, W2, Wqt, Wkt, Wvt, Wot, W1t, W2t);
  concat_bias_k<<<dim3(12), tb, 0, stream>>>(bq, bk, bv, bqkv);

  // LN1
  ln_k<<<dim3(MTOK), tb, 0, stream>>>(x, ln1g, ln1b, hbuf);

  // fused QKV projection: [4096,1024] x [3072,1024]^T -> [4096,3072] bf16
  gemm256<false, false, true><<<dim3(192), dim3(512), 0, stream>>>(
      hbuf, Wqkvt, bqkv, nullptr, QKV, MTOK, 3072, 1024);

  // V transpose -> Vt [(b*16+h)*64+d][2048]
  vtrans_k<<<dim3(32, 16, 2), tb, 0, stream>>>(QKV + 2048, Vtb);

  // attention (512 blocks x 512 threads)
  attn_k<<<dim3(512), dim3(512), 0, stream>>>(QKV, QKV + 1024, Vtb, AO);

  // O-projection + residual: x1 = x + AO @ Wo + bo  (fp32 out)  [128d3]
  gemm128d3<false, true, false><<<dim3(256), dim3(512), 0, stream>>>(
      AO, Wot, bo, x, x1, MTOK, 1024, 1024);

  // LN2
  ln_k<<<dim3(MTOK), tb, 0, stream>>>(x1, ln2g, ln2b, hbuf);

  // FFN1 + GELU: [4096,1024] x [4096,1024]^T -> [4096,4096] bf16  [d3]
  gemm256d3<true, false, true><<<dim3(256), dim3(512), 0, stream>>>(
      hbuf, W1t, b1, nullptr, gbuf, MTOK, 4096, 1024);

  // FFN2 + residual -> d_out fp32  [128d3]
  gemm128d3<false, true, false><<<dim3(256), dim3(512), 0, stream>>>(
      gbuf, W2t, b2, x1, (float*)d_out, MTOK, 1024, 4096);
}

// Round 18
// 242.905 us; speedup vs baseline: 1.0575x; 1.0575x over previous
//
#include <hip/hip_runtime.h>
#include <math.h>

#define SEQ   2048
#define DM    1024
#define LDQKV 3072
#define MTOK  4096   // B*T

typedef float  f32x4   __attribute__((ext_vector_type(4)));
typedef __bf16 bf16x8  __attribute__((ext_vector_type(8)));
typedef short  short8  __attribute__((ext_vector_type(8)));
typedef short  short4v __attribute__((ext_vector_type(4)));

__device__ __forceinline__ short f2bf(float f) {
  union { float f; unsigned u; } v; v.f = f;
  unsigned r = v.u + 0x7fffu + ((v.u >> 16) & 1u);
  return (short)(r >> 16);
}

__device__ __forceinline__ void gl_lds16(const void* g, void* l) {
  __builtin_amdgcn_global_load_lds(
      (const __attribute__((address_space(1))) void*)g,
      (__attribute__((address_space(3))) void*)l, 16, 0, 0);
}

__device__ __forceinline__ f32x4 mfma_bf16(bf16x8 a, bf16x8 b, f32x4 c) {
  return __builtin_amdgcn_mfma_f32_16x16x32_bf16(a, b, c, 0, 0, 0);
}

// GELU exact-erf via Abramowitz-Stegun 7.1.26 (|eps| <= 1.5e-7)
__device__ __forceinline__ float gelu_f(float x) {
  const float z  = x * 0.70710678118654752f;
  const float az = fabsf(z);
  const float t  = __builtin_amdgcn_rcpf(fmaf(0.3275911f, az, 1.0f));
  float p = fmaf(1.061405429f, t, -1.453152027f);
  p = fmaf(p, t, 1.421413741f);
  p = fmaf(p, t, -0.284496736f);
  p = fmaf(p, t, 0.254829592f);
  p = p * t;
  const float e = __builtin_amdgcn_exp2f(az * az * -1.4426950408889634f);
  float erfp = fmaf(-p, e, 1.0f);
  erfp = (z < 0.f) ? -erfp : erfp;
  return x * fmaf(0.5f, erfp, 0.5f);
}

// ---------------------------------------------------------------------------
// Fused weight cast+transpose, ALL 6 weights + bias concat in one launch.
// Blocks 0..3071: 64x64 transpose tiles. Block 3072: qkv bias concat.
// ---------------------------------------------------------------------------
__global__ __launch_bounds__(256) void transpose_all_k(
    const float* __restrict__ Wq, const float* __restrict__ Wk,
    const float* __restrict__ Wv, const float* __restrict__ Wo,
    const float* __restrict__ W1, const float* __restrict__ W2,
    const float* __restrict__ bq, const float* __restrict__ bk,
    const float* __restrict__ bv, float* __restrict__ bqkv,
    short* __restrict__ Wqt, short* __restrict__ Wkt, short* __restrict__ Wvt,
    short* __restrict__ Wot, short* __restrict__ W1t, short* __restrict__ W2t)
{
  const int bid = blockIdx.x;
  if (bid == 3072) {
    for (int i = threadIdx.x; i < 3072; i += 256) {
      float v = (i < 1024) ? bq[i] : (i < 2048 ? bk[i - 1024] : bv[i - 2048]);
      bqkv[i] = v;
    }
    return;
  }
  const float* W; short* Wt; int K, N, nx, ky;
  if (bid < 1024) {
    const int m = bid >> 8, r = bid & 255;
    W  = (m == 0) ? Wq : (m == 1) ? Wk : (m == 2) ? Wv : Wo;
    Wt = (m == 0) ? Wqt : (m == 1) ? Wkt : (m == 2) ? Wvt : Wot;
    K = 1024; N = 1024; nx = r & 15; ky = r >> 4;
  } else if (bid < 2048) {
    const int r = bid - 1024;
    W = W1; Wt = W1t; K = 1024; N = 4096; nx = r & 63; ky = r >> 6;
  } else {
    const int r = bid - 2048;
    W = W2; Wt = W2t; K = 4096; N = 1024; nx = r & 15; ky = r >> 4;
  }
  const int n0 = nx * 64, k0 = ky * 64;

  __shared__ float tile[64][65];
  const int tid = threadIdx.x;
  const int lr = tid >> 4, lc = (tid & 15) * 4;
#pragma unroll
  for (int i = 0; i < 4; i++) {
    const float4 v = *(const float4*)&W[(size_t)(k0 + lr + i * 16) * N + n0 + lc];
    tile[lr + i * 16][lc]     = v.x;
    tile[lr + i * 16][lc + 1] = v.y;
    tile[lr + i * 16][lc + 2] = v.z;
    tile[lr + i * 16][lc + 3] = v.w;
  }
  __syncthreads();
  const int nr = tid >> 3, ks = (tid & 7) * 8;
#pragma unroll
  for (int i = 0; i < 2; i++) {
    short8 o;
#pragma unroll
    for (int j = 0; j < 8; j++) o[j] = f2bf(tile[ks + j][nr + i * 32]);
    *(short8*)&Wt[(size_t)(n0 + nr + i * 32) * K + k0 + ks] = o;
  }
}

// ---------------------------------------------------------------------------
// LayerNorm row kernel: x fp32 [rows,1024] -> out bf16
// ---------------------------------------------------------------------------
__global__ __launch_bounds__(256) void ln_k(
    const float* __restrict__ x, const float* __restrict__ g,
    const float* __restrict__ b, short* __restrict__ out)
{
  const int row = blockIdx.x;
  const int tid = threadIdx.x;
  const float4 v = ((const float4*)(x + (size_t)row * DM))[tid];
  float s  = v.x + v.y + v.z + v.w;
  float ss = v.x * v.x + v.y * v.y + v.z * v.z + v.w * v.w;
#pragma unroll
  for (int m = 32; m >= 1; m >>= 1) { s += __shfl_xor(s, m); ss += __shfl_xor(ss, m); }
  __shared__ float red[8];
  const int wid = tid >> 6;
  if ((tid & 63) == 0) { red[wid] = s; red[4 + wid] = ss; }
  __syncthreads();
  s  = red[0] + red[1] + red[2] + red[3];
  ss = red[4] + red[5] + red[6] + red[7];
  const float mu  = s * (1.f / DM);
  const float var = ss * (1.f / DM) - mu * mu;
  const float rs  = rsqrtf(var + 1e-5f);
  const float4 gv = ((const float4*)g)[tid];
  const float4 bv = ((const float4*)b)[tid];
  short4v o;
  o[0] = f2bf((v.x - mu) * rs * gv.x + bv.x);
  o[1] = f2bf((v.y - mu) * rs * gv.y + bv.y);
  o[2] = f2bf((v.z - mu) * rs * gv.z + bv.z);
  o[3] = f2bf((v.w - mu) * rs * gv.w + bv.w);
  *(short4v*)(out + (size_t)row * DM + tid * 4) = o;
}

// ---------------------------------------------------------------------------
// V transpose: V region of QKV [token][h*64+d] -> Vt [(b*16+h)*64+d][2048]
// ---------------------------------------------------------------------------
__global__ __launch_bounds__(256) void vtrans_k(
    const short* __restrict__ V, short* __restrict__ Vt)
{
  const int b = blockIdx.z, h = blockIdx.y, t0 = blockIdx.x * 64;
  __shared__ short tile[64][72];
  const int tid = threadIdx.x;
  const int r = tid >> 2, c = (tid & 3) * 16;
  const short* src = V + (size_t)(b * SEQ + t0 + r) * LDQKV + h * 64 + c;
  *(short8*)&tile[r][c]     = *(const short8*)src;
  *(short8*)&tile[r][c + 8] = *(const short8*)(src + 8);
  __syncthreads();
  const int d = tid >> 2;
  short8 o0, o1;
#pragma unroll
  for (int k = 0; k < 8; k++) o0[k] = tile[c + k][d];
#pragma unroll
  for (int k = 0; k < 8; k++) o1[k] = tile[c + 8 + k][d];
  short* dst = Vt + (((size_t)(b * 16 + h) * 64) + d) * 2048 + t0 + c;
  *(short8*)dst       = o0;
  *(short8*)(dst + 8) = o1;
}

// ---------------------------------------------------------------------------
// GEMM 256x256, BK=64, 8 waves, 2-phase double-buffered (proven; qkv).
// ---------------------------------------------------------------------------
template <bool GELU_, bool RESID, bool OUTBF16>
__global__ __launch_bounds__(512) void gemm256(
    const short* __restrict__ A, const short* __restrict__ Bt,
    const float* __restrict__ bias, const float* __restrict__ resid,
    void* __restrict__ Cout, int M, int N, int K)
{
  __shared__ __align__(16) short Atile[2][256 * 64];
  __shared__ __align__(16) short Btile[2][256 * 64];

  const int tid = threadIdx.x, lane = tid & 63, wid = tid >> 6;
  const int wm = wid >> 2, wn = wid & 3;

  const int nbn = N >> 8;
  const int chunk = gridDim.x >> 3;
  const int swz = (blockIdx.x & 7) * chunk + (blockIdx.x >> 3);
  const int bm = (swz / nbn) * 256;
  const int bn = (swz % nbn) * 256;

  f32x4 acc[8][4] = {};

  const int srow  = wid * 8 + (lane >> 3);
  const int sslot = (lane & 7) ^ ((lane >> 3) & 7);
  const short* Asrc = A  + (size_t)(bm + srow) * K + sslot * 8;
  const short* Bsrc = Bt + (size_t)(bn + srow) * K + sslot * 8;

#define STAGE256(buf, k0)                                                     \
  {                                                                           \
    _Pragma("unroll")                                                         \
    for (int j = 0; j < 4; j++) {                                             \
      gl_lds16(Asrc + (size_t)(j * 64) * K + (k0), &Atile[buf][(j * 64 + wid * 8) * 64]); \
      gl_lds16(Bsrc + (size_t)(j * 64) * K + (k0), &Btile[buf][(j * 64 + wid * 8) * 64]); \
    }                                                                         \
  }

  const int aRowBase = (wm * 128 + (lane & 15)) * 128;
  const int bRowBase = (wn * 64  + (lane & 15)) * 128;
  const int slot0 = (((lane >> 4)    ) ^ (lane & 7)) * 16;
  const int slot1 = (((lane >> 4) + 4) ^ (lane & 7)) * 16;

#define COMPUTE256(buf)                                                       \
  {                                                                           \
    const char* Ab_ = (const char*)&Atile[buf][0];                            \
    const char* Bb_ = (const char*)&Btile[buf][0];                            \
    _Pragma("unroll")                                                         \
    for (int ks = 0; ks < 2; ks++) {                                          \
      const int sl = ks ? slot1 : slot0;                                      \
      bf16x8 a[8], b[4];                                                      \
      _Pragma("unroll")                                                       \
      for (int mi = 0; mi < 8; mi++)                                          \
        a[mi] = *(const bf16x8*)(Ab_ + aRowBase + mi * 2048 + sl);            \
      _Pragma("unroll")                                                       \
      for (int ni = 0; ni < 4; ni++)                                          \
        b[ni] = *(const bf16x8*)(Bb_ + bRowBase + ni * 2048 + sl);            \
      __builtin_amdgcn_s_setprio(1);                                          \
      _Pragma("unroll")                                                       \
      for (int mi = 0; mi < 8; mi++)                                          \
        _Pragma("unroll")                                                     \
        for (int ni = 0; ni < 4; ni++)                                        \
          acc[mi][ni] = mfma_bf16(a[mi], b[ni], acc[mi][ni]);                 \
      __builtin_amdgcn_s_setprio(0);                                          \
    }                                                                         \
  }

  STAGE256(0, 0);
  __syncthreads();

  int cur = 0;
  const int ntiles = K >> 6;
  for (int t = 1; t < ntiles; ++t) {
    STAGE256(cur ^ 1, t * 64);
    COMPUTE256(cur);
    __syncthreads();
    cur ^= 1;
  }
  COMPUTE256(cur);

#pragma unroll
  for (int mi = 0; mi < 8; mi++) {
#pragma unroll
    for (int ni = 0; ni < 4; ni++) {
      const int col = bn + wn * 64 + ni * 16 + (lane & 15);
      const float bs = bias[col];
#pragma unroll
      for (int j = 0; j < 4; j++) {
        const int row = bm + wm * 128 + mi * 16 + (lane >> 4) * 4 + j;
        float v = acc[mi][ni][j] + bs;
        if (GELU_) v = gelu_f(v);
        if (RESID) v += resid[(size_t)row * N + col];
        if (OUTBF16) ((short*)Cout)[(size_t)row * N + col] = f2bf(v);
        else         ((float*)Cout)[(size_t)row * N + col] = v;
      }
    }
  }
#undef STAGE256
#undef COMPUTE256
}

// ---------------------------------------------------------------------------
// GEMM 256x256, BK=32, 8 waves, 4-BUFFER ring, DEPTH-3 prefetch, counted
// vmcnt + raw s_barrier + sched_barrier(0). (Proven on ffn1.)
// ---------------------------------------------------------------------------
template <bool GELU_, bool RESID, bool OUTBF16>
__global__ __launch_bounds__(512) void gemm256d3(
    const short* __restrict__ A, const short* __restrict__ Bt,
    const float* __restrict__ bias, const float* __restrict__ resid,
    void* __restrict__ Cout, int M, int N, int K)
{
  __shared__ __align__(16) short Ash[4][256 * 32];   // 4 x 16 KB
  __shared__ __align__(16) short Bsh[4][256 * 32];   // 4 x 16 KB

  const int tid = threadIdx.x, lane = tid & 63, wid = tid >> 6;
  const int wm = wid >> 2, wn = wid & 3;

  const int nbn = N >> 8;
  const int chunk = gridDim.x >> 3;
  const int swz = (blockIdx.x & 7) * chunk + (blockIdx.x >> 3);
  const int bm = (swz / nbn) * 256;
  const int bn = (swz % nbn) * 256;

  f32x4 acc[8][4] = {};

  const int srow = tid >> 2;
  const int scol = ((tid & 3) ^ ((srow >> 1) & 3)) * 8;
  const short* Asrc = A  + (size_t)(bm + srow) * K + scol;
  const short* Bsrc = Bt + (size_t)(bn + srow) * K + scol;
  const int d0 = (wid * 16) * 32, d1 = (128 + wid * 16) * 32;

#define STAGE_D3(buf, k0)                                                     \
  {                                                                           \
    gl_lds16(Asrc + (k0),                   &Ash[buf][d0]);                   \
    gl_lds16(Asrc + (size_t)128 * K + (k0), &Ash[buf][d1]);                   \
    gl_lds16(Bsrc + (k0),                   &Bsh[buf][d0]);                   \
    gl_lds16(Bsrc + (size_t)128 * K + (k0), &Bsh[buf][d1]);                   \
  }

  const int rslot = ((lane >> 4) ^ ((lane >> 1) & 3)) * 8;
  const int aOff  = (wm * 128 + (lane & 15)) * 32 + rslot;
  const int bOff  = (wn * 64  + (lane & 15)) * 32 + rslot;

#define COMPUTE_D3(buf)                                                       \
  {                                                                           \
    const short* Ab_ = &Ash[buf][0];                                          \
    const short* Bb_ = &Bsh[buf][0];                                          \
    bf16x8 a[8], b[4];                                                        \
    _Pragma("unroll")                                                         \
    for (int mi = 0; mi < 8; mi++)                                            \
      a[mi] = *(const bf16x8*)(Ab_ + aOff + mi * 512);                        \
    _Pragma("unroll")                                                         \
    for (int ni = 0; ni < 4; ni++)                                            \
      b[ni] = *(const bf16x8*)(Bb_ + bOff + ni * 512);                        \
    __builtin_amdgcn_s_setprio(1);                                            \
    _Pragma("unroll")                                                         \
    for (int mi = 0; mi < 8; mi++)                                            \
      _Pragma("unroll")                                                       \
      for (int ni = 0; ni < 4; ni++)                                          \
        acc[mi][ni] = mfma_bf16(a[mi], b[ni], acc[mi][ni]);                   \
    __builtin_amdgcn_s_setprio(0);                                            \
  }

  const int nt = K >> 5;

  STAGE_D3(0, 0);
  STAGE_D3(1, 32);
  STAGE_D3(2, 64);
  asm volatile("s_waitcnt vmcnt(8)" ::: "memory");
  __builtin_amdgcn_s_barrier();
  __builtin_amdgcn_sched_barrier(0);

  for (int t = 0; t < nt; ++t) {
    if (t + 3 < nt) STAGE_D3((t + 3) & 3, (t + 3) * 32);
    COMPUTE_D3(t & 3);
    if (t + 3 < nt)      { asm volatile("s_waitcnt vmcnt(8)" ::: "memory"); }
    else if (t + 2 < nt) { asm volatile("s_waitcnt vmcnt(4)" ::: "memory"); }
    else if (t + 1 < nt) { asm volatile("s_waitcnt vmcnt(0)" ::: "memory"); }
    __builtin_amdgcn_s_barrier();
    __builtin_amdgcn_sched_barrier(0);
  }

#pragma unroll
  for (int mi = 0; mi < 8; mi++) {
#pragma unroll
    for (int ni = 0; ni < 4; ni++) {
      const int col = bn + wn * 64 + ni * 16 + (lane & 15);
      const float bs = bias[col];
#pragma unroll
      for (int j = 0; j < 4; j++) {
        const int row = bm + wm * 128 + mi * 16 + (lane >> 4) * 4 + j;
        float v = acc[mi][ni][j] + bs;
        if (GELU_) v = gelu_f(v);
        if (RESID) v += resid[(size_t)row * N + col];
        if (OUTBF16) ((short*)Cout)[(size_t)row * N + col] = f2bf(v);
        else         ((float*)Cout)[(size_t)row * N + col] = v;
      }
    }
  }
#undef STAGE_D3
#undef COMPUTE_D3
}

// ---------------------------------------------------------------------------
// GEMM narrow-N (o-proj, ffn2): 128x64 tile, 2 k-groups x 4 waves, 2-buffer
// dbuf (48 KB -> 3 blocks/CU), LDS reduction, static-indexed split epilogue.
// (r13-proven; best measured among all structural variants for this shape.)
// ---------------------------------------------------------------------------
template <bool GELU_, bool RESID, bool OUTBF16>
__global__ __launch_bounds__(512) void gemm_bt8(
    const short* __restrict__ A, const short* __restrict__ Bt,
    const float* __restrict__ bias, const float* __restrict__ resid,
    void* __restrict__ Cout, int M, int N, int K)
{
  __shared__ __align__(16) short Ab[2][2][128 * 32];
  __shared__ __align__(16) short Bb[2][2][64 * 32];
  const int tid = threadIdx.x, lane = tid & 63, wid = tid >> 6;
  const int kg = wid >> 2, w2 = wid & 3;
  const int wr = w2 >> 1, wc = w2 & 1;
  const int bm = blockIdx.x * 128, bn = blockIdx.y * 64;

  f32x4 acc[4][2] = {};

  const int r_l = lane >> 2;
  const int c8  = ((lane & 3) ^ ((lane >> 3) & 3)) * 8;
  const short* Ag0 = A  + (size_t)(bm + w2 * 32 + r_l)      * K + c8;
  const short* Ag1 = A  + (size_t)(bm + w2 * 32 + 16 + r_l) * K + c8;
  const short* Bg0 = Bt + (size_t)(bn + w2 * 16 + r_l)      * K + c8;

  const int la0 = (w2 * 32) * 32, la1 = (w2 * 32 + 16) * 32, lb0 = (w2 * 16) * 32;
  const int kbase = kg * 32;
  const int rslot = ((lane >> 4) ^ ((lane >> 1) & 3)) * 8;

  gl_lds16(Ag0 + kbase, &Ab[kg][0][la0]);
  gl_lds16(Ag1 + kbase, &Ab[kg][0][la1]);
  gl_lds16(Bg0 + kbase, &Bb[kg][0][lb0]);
  __syncthreads();

  const int nsteps = K >> 6;
  int cur = 0;
  for (int i = 1; i < nsteps; ++i) {
    const int k0 = i * 64 + kbase;
    const int nxt = cur ^ 1;
    gl_lds16(Ag0 + k0, &Ab[kg][nxt][la0]);
    gl_lds16(Ag1 + k0, &Ab[kg][nxt][la1]);
    gl_lds16(Bg0 + k0, &Bb[kg][nxt][lb0]);

    bf16x8 a[4], b[2];
#pragma unroll
    for (int mi = 0; mi < 4; mi++)
      a[mi] = *(const bf16x8*)&Ab[kg][cur][(wr * 64 + mi * 16 + (lane & 15)) * 32 + rslot];
#pragma unroll
    for (int ni = 0; ni < 2; ni++)
      b[ni] = *(const bf16x8*)&Bb[kg][cur][(wc * 32 + ni * 16 + (lane & 15)) * 32 + rslot];
#pragma unroll
    for (int mi = 0; mi < 4; mi++)
#pragma unroll
      for (int ni = 0; ni < 2; ni++)
        acc[mi][ni] = mfma_bf16(a[mi], b[ni], acc[mi][ni]);

    __syncthreads();
    cur = nxt;
  }

  {
    bf16x8 a[4], b[2];
#pragma unroll
    for (int mi = 0; mi < 4; mi++)
      a[mi] = *(const bf16x8*)&Ab[kg][cur][(wr * 64 + mi * 16 + (lane & 15)) * 32 + rslot];
#pragma unroll
    for (int ni = 0; ni < 2; ni++)
      b[ni] = *(const bf16x8*)&Bb[kg][cur][(wc * 32 + ni * 16 + (lane & 15)) * 32 + rslot];
#pragma unroll
    for (int mi = 0; mi < 4; mi++)
#pragma unroll
      for (int ni = 0; ni < 2; ni++)
        acc[mi][ni] = mfma_bf16(a[mi], b[ni], acc[mi][ni]);
  }

  __syncthreads();

  float* red = (float*)&Ab[0][0][0];
  const int lslot = w2 * 64 + lane;
  if (kg == 1) {
    *(f32x4*)&red[((0 * 256) + lslot) * 4]        = acc[0][0];
    *(f32x4*)&red[((1 * 256) + lslot) * 4]        = acc[0][1];
    *(f32x4*)&red[((2 * 256) + lslot) * 4]        = acc[1][0];
    *(f32x4*)&red[((3 * 256) + lslot) * 4]        = acc[1][1];
  } else {
    *(f32x4*)&red[((1024 + 0 * 256) + lslot) * 4] = acc[2][0];
    *(f32x4*)&red[((1024 + 1 * 256) + lslot) * 4] = acc[2][1];
    *(f32x4*)&red[((1024 + 2 * 256) + lslot) * 4] = acc[3][0];
    *(f32x4*)&red[((1024 + 3 * 256) + lslot) * 4] = acc[3][1];
  }
  __syncthreads();

#define BT8_STORE(MI, NI)                                                     \
  {                                                                           \
    const int col = bn + wc * 32 + (NI) * 16 + (lane & 15);                   \
    const float bs = bias[col];                                               \
    _Pragma("unroll")                                                         \
    for (int j = 0; j < 4; j++) {                                             \
      const int row = bm + wr * 64 + (MI) * 16 + (lane >> 4) * 4 + j;         \
      float v = acc[MI][NI][j] + bs;                                          \
      if (GELU_) v = gelu_f(v);                                               \
      if (RESID) v += resid[(size_t)row * N + col];                           \
      if (OUTBF16) ((short*)Cout)[(size_t)row * N + col] = f2bf(v);           \
      else         ((float*)Cout)[(size_t)row * N + col] = v;                 \
    }                                                                         \
  }

  if (kg == 0) {
    acc[0][0] += *(const f32x4*)&red[((0 * 256) + lslot) * 4];
    acc[0][1] += *(const f32x4*)&red[((1 * 256) + lslot) * 4];
    acc[1][0] += *(const f32x4*)&red[((2 * 256) + lslot) * 4];
    acc[1][1] += *(const f32x4*)&red[((3 * 256) + lslot) * 4];
    BT8_STORE(0, 0); BT8_STORE(0, 1); BT8_STORE(1, 0); BT8_STORE(1, 1);
  } else {
    acc[2][0] += *(const f32x4*)&red[((1024 + 0 * 256) + lslot) * 4];
    acc[2][1] += *(const f32x4*)&red[((1024 + 1 * 256) + lslot) * 4];
    acc[3][0] += *(const f32x4*)&red[((1024 + 2 * 256) + lslot) * 4];
    acc[3][1] += *(const f32x4*)&red[((1024 + 3 * 256) + lslot) * 4];
    BT8_STORE(2, 0); BT8_STORE(2, 1); BT8_STORE(3, 0); BT8_STORE(3, 1);
  }
#undef BT8_STORE
}

// ---------------------------------------------------------------------------
// Flash attention v4.1 (proven r13/r14 best): 8 waves / 128 q-rows,
// swapped-QK^T, KVBLK=128, defer-max, in-register P, K+V dbuf LDS,
// chunked XCD swizzle, native exp2.
// ---------------------------------------------------------------------------
__global__ __launch_bounds__(512, 4) void attn_k(
    const short* __restrict__ Qg, const short* __restrict__ Kg,
    const short* __restrict__ Vt, short* __restrict__ Og)
{
  const int phys = blockIdx.x;
  const int lg = (phys & 7) * 64 + (phys >> 3);
  const int q0 = (lg & 15) * 128;
  const int h  = (lg >> 4) & 15;
  const int b  = lg >> 8;

  const int tid = threadIdx.x, lane = tid & 63, w = tid >> 6;
  const int qlane = lane & 15, g = lane >> 4;

  __shared__ __align__(16) short Kl[2][128 * 64];
  __shared__ __align__(16) short Vl[2][64 * 128];

  const size_t qrow = (size_t)(b * SEQ + q0 + w * 16 + qlane) * LDQKV + h * 64;
  const bf16x8 qf0 = *(const bf16x8*)&Qg[qrow + g * 8];
  const bf16x8 qf1 = *(const bf16x8*)&Qg[qrow + 32 + g * 8];

  const int kslot = (lane & 7) ^ ((lane >> 3) & 7);
  const short* Kg_a[2];
#pragma unroll
  for (int i = 0; i < 2; i++) {
    const int r  = i * 64 + w * 8 + (lane >> 3);
    const int kc = r >> 4, gr = (r >> 2) & 3, jr = r & 3;
    const int a  = 32 * (kc & 3) + 8 * gr + 4 * (kc >> 2) + jr;
    Kg_a[i] = Kg + ((size_t)(b * SEQ) + a) * LDQKV + h * 64 + kslot * 8;
  }
  const short* Vg_s[2];
#pragma unroll
  for (int i = 0; i < 2; i++) {
    const int d  = i * 32 + w * 4 + (lane >> 4);
    const int vs = (lane & 15) ^ (d & 15);
    Vg_s[i] = Vt + ((size_t)(b * 16 + h) * 64 + d) * 2048 + vs * 8;
  }

  float m_run = -1e30f, l_run = 0.f;
  f32x4 oacc[4] = {};
  const float C = 0.125f * 1.44269504088896f;

#pragma unroll
  for (int i = 0; i < 2; i++) {
    gl_lds16(Kg_a[i], &Kl[0][(i * 64 + w * 8) * 64]);
    gl_lds16(Vg_s[i], &Vl[0][(i * 32 + w * 4) * 128]);
  }
  __syncthreads();

  int cur = 0;
  for (int kt = 0; kt < SEQ; kt += 128) {
    const int nxt = cur ^ 1;
    if (kt + 128 < SEQ) {
#pragma unroll
      for (int i = 0; i < 2; i++) {
        gl_lds16(Kg_a[i] + (size_t)(kt + 128) * LDQKV, &Kl[nxt][(i * 64 + w * 8) * 64]);
        gl_lds16(Vg_s[i] + (kt + 128),                 &Vl[nxt][(i * 32 + w * 4) * 128]);
      }
    }
    const char* KbC = (const char*)&Kl[cur][0];
    const char* VbC = (const char*)&Vl[cur][0];

    f32x4 s[8];
#pragma unroll
    for (int kc = 0; kc < 8; kc++) {
      const int kr = kc * 16 + qlane;
      const char* kp = KbC + kr * 128;
      const int sw = (kr & 7) << 4;
      bf16x8 kf0 = *(const bf16x8*)(kp + ((g * 16) ^ sw));
      bf16x8 kf1 = *(const bf16x8*)(kp + ((64 + g * 16) ^ sw));
      f32x4 z = {};
      z = mfma_bf16(kf0, qf0, z);
      z = mfma_bf16(kf1, qf1, z);
      s[kc] = z;
    }

    f32x4 m4 = s[0];
#pragma unroll
    for (int kc = 1; kc < 8; kc++) {
      m4[0] = fmaxf(m4[0], s[kc][0]); m4[1] = fmaxf(m4[1], s[kc][1]);
      m4[2] = fmaxf(m4[2], s[kc][2]); m4[3] = fmaxf(m4[3], s[kc][3]);
    }
    float mt = fmaxf(fmaxf(m4[0], m4[1]), fmaxf(m4[2], m4[3]));
    mt = fmaxf(mt, __shfl_xor(mt, 16));
    mt = fmaxf(mt, __shfl_xor(mt, 32));

    if (!__all(mt - m_run <= 40.0f)) {
      const float mnew = fmaxf(m_run, mt);
      const float r = __builtin_amdgcn_exp2f((m_run - mnew) * C);
      m_run = mnew;
      l_run *= r;
#pragma unroll
      for (int j = 0; j < 4; j++) {
        const float rj = __shfl(r, g * 4 + j);
#pragma unroll
        for (int dt = 0; dt < 4; dt++) oacc[dt][j] *= rj;
      }
    }

    const float nmc = -m_run * C;
    float rs = 0.f;
    unsigned pw[4][4];
#pragma unroll
    for (int kc = 0; kc < 8; kc++) {
      f32x4 p;
#pragma unroll
      for (int j = 0; j < 4; j++) p[j] = __builtin_amdgcn_exp2f(fmaf(s[kc][j], C, nmc));
      rs += (p[0] + p[1]) + (p[2] + p[3]);
      unsigned w0, w1;
      asm("v_cvt_pk_bf16_f32 %0, %1, %2" : "=v"(w0) : "v"(p[0]), "v"(p[1]));
      asm("v_cvt_pk_bf16_f32 %0, %1, %2" : "=v"(w1) : "v"(p[2]), "v"(p[3]));
      pw[kc & 3][2 * (kc >> 2) + 0] = w0;
      pw[kc & 3][2 * (kc >> 2) + 1] = w1;
    }
    rs += __shfl_xor(rs, 16);
    rs += __shfl_xor(rs, 32);
    l_run += rs;

#pragma unroll
    for (int ks = 0; ks < 4; ks++) {
      union { unsigned u[4]; bf16x8 v; } pf;
      pf.u[0] = pw[ks][0]; pf.u[1] = pw[ks][1];
      pf.u[2] = pw[ks][2]; pf.u[3] = pw[ks][3];
#pragma unroll
      for (int dt = 0; dt < 4; dt++) {
        const int vr = dt * 16 + qlane;
        bf16x8 vf = *(const bf16x8*)(VbC + vr * 256 + ((64 * ks + 16 * g) ^ ((vr & 15) << 4)));
        oacc[dt] = mfma_bf16(pf.v, vf, oacc[dt]);
      }
    }

    __syncthreads();
    cur = nxt;
  }

  const float linv = 1.f / l_run;
#pragma unroll
  for (int j = 0; j < 4; j++) {
    const float lj = __shfl(linv, g * 4 + j);
    const int tok = q0 + w * 16 + g * 4 + j;
#pragma unroll
    for (int dt = 0; dt < 4; dt++)
      Og[(size_t)(b * SEQ + tok) * DM + h * 64 + dt * 16 + qlane] = f2bf(oacc[dt][j] * lj);
  }
}

// ---------------------------------------------------------------------------
extern "C" void kernel_launch(void* const* d_in, const int* in_sizes, int n_in,
                              void* d_out, int out_size, void* d_ws, size_t ws_size,
                              hipStream_t stream)
{
  const float* x    = (const float*)d_in[0];
  const float* Wq   = (const float*)d_in[1];
  const float* bq   = (const float*)d_in[2];
  const float* Wk   = (const float*)d_in[3];
  const float* bk   = (const float*)d_in[4];
  const float* Wv   = (const float*)d_in[5];
  const float* bv   = (const float*)d_in[6];
  const float* Wo   = (const float*)d_in[7];
  const float* bo   = (const float*)d_in[8];
  const float* W1   = (const float*)d_in[9];
  const float* b1   = (const float*)d_in[10];
  const float* W2   = (const float*)d_in[11];
  const float* b2   = (const float*)d_in[12];
  const float* ln1g = (const float*)d_in[13];
  const float* ln1b = (const float*)d_in[14];
  const float* ln2g = (const float*)d_in[15];
  const float* ln2b = (const float*)d_in[16];

  char* ws = (char*)d_ws;
  const size_t MB = 1024 * 1024;
  short* Wqkvt = (short*)(ws + 0 * MB);           // [3072][1024] bf16
  short* Wqt   = Wqkvt;
  short* Wkt   = (short*)(ws + 2 * MB);
  short* Wvt   = (short*)(ws + 4 * MB);
  short* Wot   = (short*)(ws + 6 * MB);           // [1024][1024]
  short* W1t   = (short*)(ws + 8 * MB);           // [4096][1024]
  short* W2t   = (short*)(ws + 16 * MB);          // [1024][4096]
  short* hbuf  = (short*)(ws + 24 * MB);          // [4096][1024] bf16
  short* QKV   = (short*)(ws + 32 * MB);          // [4096][3072] bf16
  short* AO    = (short*)(ws + 56 * MB);          // [4096][1024] bf16
  float* x1    = (float*)(ws + 64 * MB);          // [4096][1024] fp32 (after attn)
  short* Vtb   = (short*)(ws + 64 * MB);          // [2048][2048] bf16 Vt
  float* bqkv  = (float*)(ws + 80 * MB);          // [3072] fp32
  short* gbuf  = (short*)(ws + 32 * MB);          // [4096][4096] bf16, aliases QKV+AO

  dim3 tb(256);

  // all 6 weight transposes + bias concat in one launch
  transpose_all_k<<<dim3(3073), tb, 0, stream>>>(
      Wq, Wk, Wv, Wo, W1, W2, bq, bk, bv, bqkv,
      Wqt, Wkt, Wvt, Wot, W1t, W2t);

  // LN1
  ln_k<<<dim3(MTOK), tb, 0, stream>>>(x, ln1g, ln1b, hbuf);

  // fused QKV projection: [4096,1024] x [3072,1024]^T -> [4096,3072] bf16
  gemm256<false, false, true><<<dim3(192), dim3(512), 0, stream>>>(
      hbuf, Wqkvt, bqkv, nullptr, QKV, MTOK, 3072, 1024);

  // V transpose -> Vt [(b*16+h)*64+d][2048]
  vtrans_k<<<dim3(32, 16, 2), tb, 0, stream>>>(QKV + 2048, Vtb);

  // attention (512 blocks x 512 threads)
  attn_k<<<dim3(512), dim3(512), 0, stream>>>(QKV, QKV + 1024, Vtb, AO);

  // O-projection + residual: x1 = x + AO @ Wo + bo  (fp32 out)
  gemm_bt8<false, true, false><<<dim3(32, 16), dim3(512), 0, stream>>>(
      AO, Wot, bo, x, x1, MTOK, 1024, 1024);

  // LN2
  ln_k<<<dim3(MTOK), tb, 0, stream>>>(x1, ln2g, ln2b, hbuf);

  // FFN1 + GELU: [4096,1024] x [4096,1024]^T -> [4096,4096] bf16  [d3]
  gemm256d3<true, false, true><<<dim3(256), dim3(512), 0, stream>>>(
      hbuf, W1t, b1, nullptr, gbuf, MTOK, 4096, 1024);

  // FFN2 + residual -> d_out fp32
  gemm_bt8<false, true, false><<<dim3(32, 16), dim3(512), 0, stream>>>(
      gbuf, W2t, b2, x1, (float*)d_out, MTOK, 1024, 4096);
}